// Round 12
// baseline (98.563 us; speedup 1.0000x reference)
//
#include <hip/hip_runtime.h>
#include <math.h>

// B=16, O=24, V=2, P0=32, P1=64, P2=64, R=3, C=16, UI=1, BI=2
// NUM_IN=288, P=552 (p=a*23+j, bb=j+(j>=a), aadj=a-(a>bb))
// conj(b,p,r,c) = U1(b,a)·U2(b,bb)·T3(b,a,j)·T4(b,bb,aadj)
//   U1: nullary(i<32)+unary[a] segs (i 32..96); U2: unary[bb] seg (i 96..160)
//   T3: binary[a][j] seg (i 160..224); T4: binary[bb][aadj] seg (i 224..288)
// All factors depend only on INPUT rows -> fully block-local computation.
// out: [nullary_out(16) | unary_out(16*24) | binary_out(16*24*23)]

#define XROW 68

__device__ __forceinline__ float sigm(float x) { return 1.0f / (1.0f + expf(-x)); }

// softmax(ak[r][c][i][0..2]/T) -> (d=s0-s1, e=s1+s2); term = fma(x,d,e)
__device__ __forceinline__ float2 dke_of(const float* __restrict__ akp, float invT) {
    float a0 = akp[0] * invT, a1 = akp[1] * invT, a2 = akp[2] * invT;
    float mx = fmaxf(a0, fmaxf(a1, a2));
    float e0 = expf(a0 - mx), e1 = expf(a1 - mx), e2 = expf(a2 - mx);
    float inv = 1.0f / (e0 + e1 + e2);
    float s0 = e0 * inv, s1 = e1 * inv, s2 = e2 * inv;
    return make_float2(s0 - s1, s1 + s2);
}

// ---------------- Kernel 1: everything except the cross-a nullary fold ----------------
// grid: 16*24 = 384 blocks (b,a). block: 256 threads.
__global__ __launch_bounds__(256) void main_kernel(const float* __restrict__ nullary,
                                                   const float* __restrict__ unary,
                                                   const float* __restrict__ binary,
                                                   const float* __restrict__ ak,
                                                   const float* __restrict__ orK,
                                                   const float* __restrict__ temp,
                                                   float* __restrict__ out,
                                                   float* __restrict__ ws0) {
    __shared__ float ck[128 * 16 * 6];   // 49.2 KB: U-phase seg2 (first half); T-phase seg3|seg4
    __shared__ float xr[48 * XROW];      // 13.1 KB: U-phase unary rows+nullary; T-phase binary rows
    __shared__ float U2sh[24 * 48];      // 4.6 KB
    __shared__ float U1sh[48];
    __shared__ float pu1[4][48];
    __shared__ float red0[16][16];
    __shared__ float red1[16][16];

    const int tid = threadIdx.x;
    const int b = blockIdx.x / 24;
    const int a = blockIdx.x % 24;
    const float invT = 1.0f / temp[0];

    // ======== U-stage: seg2 coeffs (i=96..160) + unary rows + nullary ========
    for (int idx = tid; idx < 64 * 16; idx += 256) {
        int i2 = idx >> 4, c = idx & 15;
        float* q = &ck[(size_t)idx * 6];
#pragma unroll
        for (int r = 0; r < 3; ++r) {
            float2 de = dke_of(ak + (((size_t)(r * 16 + c) * 288) + 96 + i2) * 3, invT);
            q[2 * r] = de.x; q[2 * r + 1] = de.y;
        }
        (void)i2;
    }
    for (int idx = tid; idx < 24 * 16; idx += 256) {
        int row = idx >> 4, q4 = idx & 15;
        float4 v = *(const float4*)(unary + ((size_t)b * 24 + row) * 64 + q4 * 4);
        *(float4*)&xr[row * XROW + q4 * 4] = v;
    }
    if (tid < 8) {
        float4 v = *(const float4*)(nullary + b * 32 + tid * 4);
        *(float4*)&xr[24 * XROW + tid * 4] = v;
    }
    __syncthreads();

    // ---- U1 partials: wave iq handles i-quarter; lanes rc<48 = (r,c) ----
    {
        int iq = tid >> 6, rc = tid & 63;
        if (rc < 48) {
            int c = rc & 15, r = rc >> 4;
            float acc = 1.0f;
            for (int i = iq * 8; i < iq * 8 + 8; ++i) {           // seg0: nullary
                float2 de = dke_of(ak + (((size_t)(r * 16 + c) * 288) + i) * 3, invT);
                acc *= fmaf(xr[24 * XROW + i], de.x, de.y);
            }
            for (int i1 = iq * 16; i1 < iq * 16 + 16; ++i1) {     // seg1: unary[a]
                float2 de = dke_of(ak + (((size_t)(r * 16 + c) * 288) + 32 + i1) * 3, invT);
                acc *= fmaf(xr[a * XROW + i1], de.x, de.y);
            }
            pu1[iq][rc] = acc;
        }
    }
    // ---- U2 for all 24 rows: pairs (row, rc) ----
    for (int pair = tid; pair < 24 * 48; pair += 256) {
        int row = pair / 48, rc = pair % 48;
        int c = rc & 15, r = rc >> 4;
        float acc = 1.0f;
        for (int i2 = 0; i2 < 64; ++i2) {
            const float* k = &ck[((size_t)(i2 * 16 + c)) * 6 + 2 * r];
            acc *= fmaf(xr[row * XROW + i2], k[0], k[1]);
        }
        U2sh[row * 48 + rc] = acc;
    }
    __syncthreads();
    if (tid < 48) U1sh[tid] = pu1[0][tid] * pu1[1][tid] * pu1[2][tid] * pu1[3][tid];

    // ======== T-stage: seg3+seg4 coeffs (i=160..288) + binary rows ========
    for (int idx = tid; idx < 128 * 16; idx += 256) {
        int i34 = idx >> 4, c = idx & 15;
        float* q = &ck[(size_t)idx * 6];
#pragma unroll
        for (int r = 0; r < 3; ++r) {
            float2 de = dke_of(ak + (((size_t)(r * 16 + c) * 288) + 160 + i34) * 3, invT);
            q[2 * r] = de.x; q[2 * r + 1] = de.y;
        }
    }
    for (int idx = tid; idx < 48 * 16; idx += 256) {
        int row = idx >> 4, q4 = idx & 15;
        const float* src;
        if (row < 24) {
            int j = row < 23 ? row : 22;
            src = binary + (((size_t)b * 24 + a) * 23 + j) * 64 + q4 * 4;
        } else {
            int jj = row - 24 < 23 ? row - 24 : 22;
            int bb = jj + (jj >= a ? 1 : 0);
            int aadj = (a > bb) ? (a - 1) : a;
            src = binary + (((size_t)b * 24 + bb) * 23 + aadj) * 64 + q4 * 4;
        }
        float4 v = *(const float4*)src;
        *(float4*)&xr[row * XROW + q4 * 4] = v;
    }
    __syncthreads();

    // ======== T-compute: thread (pj,c); own T3 + partner T4 for j1=pj, j2=pj+16 ========
    const int pj = tid >> 4;
    const int c = tid & 15;
    const int j1 = pj;
    const int j2 = pj + 16;
    const int j2e = j2 < 23 ? j2 : 22;

    float t3a[2][3], t4a[2][3];
#pragma unroll
    for (int k = 0; k < 2; ++k)
#pragma unroll
        for (int r = 0; r < 3; ++r) { t3a[k][r] = 1.0f; t4a[k][r] = 1.0f; }

    for (int i0 = 0; i0 < 16; ++i0) {
        float4 xo1 = *(const float4*)&xr[j1 * XROW + i0 * 4];
        float4 xo2 = *(const float4*)&xr[j2e * XROW + i0 * 4];
        float4 xp1 = *(const float4*)&xr[(24 + j1) * XROW + i0 * 4];
        float4 xp2 = *(const float4*)&xr[(24 + j2e) * XROW + i0 * 4];
        const float* xo1p = (const float*)&xo1;
        const float* xo2p = (const float*)&xo2;
        const float* xp1p = (const float*)&xp1;
        const float* xp2p = (const float*)&xp2;
#pragma unroll
        for (int s = 0; s < 4; ++s) {
            const int i = i0 * 4 + s;
            const float2* k3 = (const float2*)&ck[((size_t)(i * 16 + c)) * 6];
            const float2* k4 = (const float2*)&ck[((size_t)((64 + i) * 16 + c)) * 6];
            float2 k30 = k3[0], k31 = k3[1], k32 = k3[2];
            float2 k40 = k4[0], k41 = k4[1], k42 = k4[2];
            float a1 = xo1p[s], a2 = xo2p[s], p1 = xp1p[s], p2 = xp2p[s];
            t3a[0][0] *= fmaf(a1, k30.x, k30.y);
            t3a[0][1] *= fmaf(a1, k31.x, k31.y);
            t3a[0][2] *= fmaf(a1, k32.x, k32.y);
            t3a[1][0] *= fmaf(a2, k30.x, k30.y);
            t3a[1][1] *= fmaf(a2, k31.x, k31.y);
            t3a[1][2] *= fmaf(a2, k32.x, k32.y);
            t4a[0][0] *= fmaf(p1, k40.x, k40.y);
            t4a[0][1] *= fmaf(p1, k41.x, k41.y);
            t4a[0][2] *= fmaf(p1, k42.x, k42.y);
            t4a[1][0] *= fmaf(p2, k40.x, k40.y);
            t4a[1][1] *= fmaf(p2, k41.x, k41.y);
            t4a[1][2] *= fmaf(p2, k42.x, k42.y);
        }
    }

    // ======== Epilogue ========
    const float T = temp[0];
    const float ok2 = sigm(orK[32 + c] / T);
    float au1 = 1.0f, au0 = 1.0f;

#pragma unroll
    for (int k = 0; k < 2; ++k) {
        int j = (k == 0) ? j1 : j2;
        int jv = (k == 0) ? j1 : j2e;
        int bb = jv + (jv >= a ? 1 : 0);
        float c0 = U1sh[c]      * U2sh[bb * 48 + c]      * t3a[k][0] * t4a[k][0];
        float c1 = U1sh[16 + c] * U2sh[bb * 48 + 16 + c] * t3a[k][1] * t4a[k][1];
        float c2 = U1sh[32 + c] * U2sh[bb * 48 + 32 + c] * t3a[k][2] * t4a[k][2];
        float w = 1.0f - c2 * ok2;
#pragma unroll
        for (int off = 1; off < 16; off <<= 1) w *= __shfl_xor(w, off, 16);
        if (c == 0 && j < 23) out[400 + ((size_t)b * 24 + a) * 23 + j] = 1.0f - w;
        if (j < 23) {
            au1 *= (1.0f - c1);
            au0 *= (1.0f - c0);
        }
    }

    red1[pj][c] = au1;
    red0[pj][c] = au0;
    __syncthreads();

    if (tid < 16) {
        int cc = tid;
        float p1 = 1.0f, p0 = 1.0f;
#pragma unroll
        for (int q = 0; q < 16; ++q) { p1 *= red1[q][cc]; p0 *= red0[q][cc]; }
        float ok1 = sigm(orK[16 + cc] / T);
        float w = 1.0f - (1.0f - p1) * ok1;
#pragma unroll
        for (int off = 1; off < 16; off <<= 1) w *= __shfl_xor(w, off, 16);
        if (cc == 0) out[16 + (size_t)b * 24 + a] = 1.0f - w;
        ws0[((size_t)b * 24 + a) * 16 + cc] = p0;
    }
}

// ---------------- Kernel 2: nullary finish (cross-a fold) ----------------
__global__ __launch_bounds__(256) void final_kernel(const float* __restrict__ ws0,
                                                    const float* __restrict__ orK,
                                                    const float* __restrict__ temp,
                                                    float* __restrict__ out) {
    int tid = threadIdx.x;       // 256 = 16 b * 16 c
    int b = tid >> 4, c = tid & 15;
    float p = 1.0f;
#pragma unroll
    for (int a = 0; a < 24; ++a) p *= ws0[((size_t)b * 24 + a) * 16 + c];
    float T = temp[0];
    float ok0 = sigm(orK[c] / T);
    float w = 1.0f - (1.0f - p) * ok0;
#pragma unroll
    for (int off = 1; off < 16; off <<= 1) w *= __shfl_xor(w, off, 16);
    if (c == 0) out[b] = 1.0f - w;
}

extern "C" void kernel_launch(void* const* d_in, const int* in_sizes, int n_in,
                              void* d_out, int out_size, void* d_ws, size_t ws_size,
                              hipStream_t stream) {
    const float* nullary = (const float*)d_in[0];   // (16,32)
    const float* unary   = (const float*)d_in[1];   // (16,24,64)
    const float* binary  = (const float*)d_in[2];   // (16,24,23,64)
    const float* ak      = (const float*)d_in[3];   // (3,16,288,3)
    const float* orK     = (const float*)d_in[4];   // (3,16)
    const float* temp    = (const float*)d_in[5];   // scalar

    float* out = (float*)d_out;                     // 16 + 384 + 8832 floats
    float* ws0 = (float*)d_ws;                      // 16*24*16 = 6144 floats

    main_kernel<<<16 * 24, 256, 0, stream>>>(nullary, unary, binary, ak, orK, temp, out, ws0);
    final_kernel<<<1, 256, 0, stream>>>(ws0, orK, temp, out);
}